// Round 6
// baseline (359.398 us; speedup 1.0000x reference)
//
#include <hip/hip_runtime.h>
#include <cstdint>

#define BB 2048
#define TT 200
#define DD 128
#define H1 128
#define H2 64
#define MASK_PAD -4294967295.0f

typedef __attribute__((ext_vector_type(8))) short short8;
typedef __attribute__((ext_vector_type(4))) float floatx4;

#define ATTN_OFF 57344  // float offset of attn[2048][200] in ws

static __device__ __forceinline__ unsigned short f2bf(float x) {
  union { float f; unsigned int u; } v; v.f = x;
  unsigned int r = v.u + 0x7FFF + ((v.u >> 16) & 1);  // RNE
  return (unsigned short)(r >> 16);
}

// ---------------------------------------------------------------------------
// Fold kernel -> ws:
//   Wqac[d][h] = W0a[d][h] + W0c[d][h]          fp32 [128][128] @ float 0
//   WkT [h][d] = (W0b - W0c)[d][h]              fp32 [128][128] @ float 16384
//   WdT [h][d] = W0d[d][h]                      fp32 [128][128] @ float 32768
//   W1tb[g][h] = bf16(W1[h][g])                 bf16 [64][128]  @ float 49152
// ---------------------------------------------------------------------------
__global__ void din_fold(const float* __restrict__ W0,
                         const float* __restrict__ W1,
                         float* __restrict__ ws) {
  int i = blockIdx.x * blockDim.x + threadIdx.x;
  if (i < 16384) {
    int d = i >> 7, h = i & 127;
    ws[i] = W0[d * 128 + h] + W0[(256 + d) * 128 + h];
  } else if (i < 32768) {
    int j = i - 16384; int h = j >> 7, d = j & 127;
    ws[16384 + j] = W0[(128 + d) * 128 + h] - W0[(256 + d) * 128 + h];
  } else if (i < 49152) {
    int j = i - 32768; int h = j >> 7, d = j & 127;
    ws[32768 + j] = W0[(384 + d) * 128 + h];
  } else if (i < 57344) {
    int j = i - 49152; int g = j >> 7, h = j & 127;
    ((unsigned short*)(ws + 49152))[j] = f2bf(W1[h * 64 + g]);
  }
}

// ---------------------------------------------------------------------------
// Kernel A: logits + softmax -> attn weights. One block per b, 4 waves.
// Barrier-free main loop: W_b = bf16(WkT + q_d*WdT) staged once in LDS
// (swizzled); each wave independently owns 16-row M-tiles (mt = w, w+4, ...),
// computes full-width GEMM1 (B from LDS), PReLU, in-wave LDS transpose,
// GEMM2 (B direct from L2), PReLU, per-row reduce -> logits. One barrier
// before softmax.
// ---------------------------------------------------------------------------
__global__ __launch_bounds__(256, 2) void din_logits(
    const float* __restrict__ query, const float* __restrict__ key,
    const int* __restrict__ mask,
    const float* __restrict__ b0, const float* __restrict__ a0,
    const float* __restrict__ b1, const float* __restrict__ a1,
    const float* __restrict__ Wout, const float* __restrict__ bout,
    const float* __restrict__ ws, float* __restrict__ attn_out) {
  const int b = blockIdx.x;
  const int tid = threadIdx.x;
  const int w = tid >> 6;
  const int l = tid & 63;

  __shared__ unsigned short Wb[128 * 128];   // 32 KB folded W_b bf16 (swz)
  __shared__ unsigned short A2[4][16 * 128]; // 16 KB per-wave H0 buffers (swz)
  __shared__ float qs[DD];
  __shared__ float qas2[2][H1];
  __shared__ float logitsAll[208];
  __shared__ float red4[8];

  const float* Wqac = ws;
  const float* WkT  = ws + 16384;
  const float* WdT  = ws + 32768;
  const unsigned short* W1tb = (const unsigned short*)(ws + 49152);

  // ---- stage q ----
  if (tid < DD) qs[tid] = query[(size_t)b * DD + tid];
  __syncthreads();

  // ---- build W_b into LDS: bf16(WkT[h][d] + q[d]*WdT[h][d]), swizzled ----
  #pragma unroll
  for (int j = 0; j < 16; ++j) {
    int flat = j * 1024 + tid * 4;          // coalesced float4 index
    int h = flat >> 7, d = flat & 127;
    float4 kv = *(const float4*)(WkT + flat);
    float4 dv = *(const float4*)(WdT + flat);
    ushort4 u;
    u.x = f2bf(kv.x + qs[d] * dv.x);
    u.y = f2bf(kv.y + qs[d + 1] * dv.y);
    u.z = f2bf(kv.z + qs[d + 2] * dv.z);
    u.w = f2bf(kv.w + qs[d + 3] * dv.w);
    *(ushort4*)((char*)Wb + h * 256 + ((d * 2) ^ ((h & 7) << 4))) = u;
  }

  // ---- qA: qas[h] = b0[h] + sum_d q[d]*Wqac[d][h] (coalesced over h) ----
  {
    int h = tid & 127, half = tid >> 7;
    float acc = half ? 0.0f : b0[h];
    const float* wq = Wqac + half * 64 * 128 + h;
    #pragma unroll 8
    for (int d = 0; d < 64; ++d) acc += qs[half * 64 + d] * wq[d * 128];
    qas2[half][h] = acc;
  }
  __syncthreads();  // Wb + qas ready

  const int swz = (l & 7) << 4;
  const int kgrp = (l >> 4);          // 0..3
  char* a2b = (char*)A2[w];           // this wave's private transpose buffer

  // =============== barrier-free per-wave M-tile loop ===============
  #pragma unroll 1
  for (int mt = w; mt < 13; mt += 4) {
    // ---- A-frags: batch 8 float4 loads from key, cvt to bf16 ----
    int trow = mt * 16 + (l & 15);
    int rowc = trow > 199 ? 199 : trow;
    const float* arow = key + ((size_t)b * TT + rowc) * DD + kgrp * 8;
    float4 fa[8];
    #pragma unroll
    for (int ks = 0; ks < 4; ++ks) {
      fa[2 * ks]     = *(const float4*)(arow + ks * 32);
      fa[2 * ks + 1] = *(const float4*)(arow + ks * 32 + 4);
    }
    short8 af[4];
    #pragma unroll
    for (int ks = 0; ks < 4; ++ks) {
      float4 f0 = fa[2 * ks], f1 = fa[2 * ks + 1];
      short8 t;
      t[0] = (short)f2bf(f0.x); t[1] = (short)f2bf(f0.y);
      t[2] = (short)f2bf(f0.z); t[3] = (short)f2bf(f0.w);
      t[4] = (short)f2bf(f1.x); t[5] = (short)f2bf(f1.y);
      t[6] = (short)f2bf(f1.z); t[7] = (short)f2bf(f1.w);
      af[ks] = t;
    }

    // ---- GEMM1: full width, 8 n-tiles, B from LDS ----
    floatx4 acc1[8];
    #pragma unroll
    for (int nt = 0; nt < 8; ++nt) acc1[nt] = (floatx4)(0.0f);
    #pragma unroll
    for (int ks = 0; ks < 4; ++ks) {
      #pragma unroll
      for (int nt = 0; nt < 8; ++nt) {
        int h = nt * 16 + (l & 15);
        short8 bf = *(const short8*)((const char*)Wb + h * 256 +
                                     ((ks * 64 + kgrp * 16) ^ swz));
        acc1[nt] = __builtin_amdgcn_mfma_f32_16x16x32_bf16(af[ks], bf, acc1[nt], 0, 0, 0);
      }
    }

    // ---- epilogue 1: +qA, PReLU(a0), write H0 to private LDS (swz) ----
    #pragma unroll
    for (int nt = 0; nt < 8; ++nt) {
      int h = nt * 16 + (l & 15);
      float qa = qas2[0][h] + qas2[1][h];
      #pragma unroll
      for (int r = 0; r < 4; ++r) {
        int t_loc = kgrp * 4 + r;
        int tg = mt * 16 + t_loc;
        float v = acc1[nt][r] + qa;
        float a = (tg < TT) ? a0[tg * H1 + h] : 0.0f;
        v = v > 0.0f ? v : a * v;
        *(unsigned short*)(a2b + t_loc * 256 + ((h * 2) ^ ((t_loc & 7) << 4))) = f2bf(v);
      }
    }

    // ---- GEMM2: A from private LDS, B direct from global (L2) ----
    short8 a2f[4];
    #pragma unroll
    for (int ks = 0; ks < 4; ++ks) {
      a2f[ks] = *(const short8*)(a2b + (l & 15) * 256 +
                                 ((ks * 64 + kgrp * 16) ^ swz));
    }
    float p[4] = {0.f, 0.f, 0.f, 0.f};
    #pragma unroll
    for (int nt = 0; nt < 4; ++nt) {
      int g = nt * 16 + (l & 15);
      floatx4 acc2 = (floatx4)(0.0f);
      #pragma unroll
      for (int ks = 0; ks < 4; ++ks) {
        short8 bf = *(const short8*)(W1tb + g * 128 + ks * 32 + kgrp * 8);
        acc2 = __builtin_amdgcn_mfma_f32_16x16x32_bf16(a2f[ks], bf, acc2, 0, 0, 0);
      }
      float b1v = b1[g], wov = Wout[g];
      #pragma unroll
      for (int r = 0; r < 4; ++r) {
        int tg = mt * 16 + kgrp * 4 + r;
        float x = acc2[r] + b1v;
        float a = (tg < TT) ? a1[tg * H2 + g] : 0.0f;
        x = x > 0.0f ? x : a * x;
        p[r] += x * wov;
      }
    }
    // ---- reduce over the 16 g-lanes; lanes l&15==0 write logits ----
    #pragma unroll
    for (int m = 1; m < 16; m <<= 1) {
      #pragma unroll
      for (int r = 0; r < 4; ++r) p[r] += __shfl_xor(p[r], m);
    }
    if ((l & 15) == 0) {
      #pragma unroll
      for (int r = 0; r < 4; ++r) {
        int tg = mt * 16 + kgrp * 4 + r;
        if (tg < TT) {
          int mk = mask[(size_t)b * TT + tg];
          logitsAll[tg] = (mk == 0) ? MASK_PAD : (bout[0] + p[r]);
        }
      }
    }
  }
  __syncthreads();

  // =================== softmax -> normalized attn ===================
  float lv = (tid < TT) ? logitsAll[tid] : -INFINITY;
  {
    float m = lv;
    #pragma unroll
    for (int off = 32; off >= 1; off >>= 1) m = fmaxf(m, __shfl_xor(m, off));
    if (l == 0) red4[w] = m;
  }
  __syncthreads();
  float mx = fmaxf(fmaxf(red4[0], red4[1]), fmaxf(red4[2], red4[3]));
  float e = (tid < TT) ? __expf(lv - mx) : 0.0f;
  {
    float s = e;
    #pragma unroll
    for (int off = 32; off >= 1; off >>= 1) s += __shfl_xor(s, off);
    if (l == 0) red4[4 + w] = s;
  }
  __syncthreads();
  float denom = red4[4] + red4[5] + red4[6] + red4[7];
  float inv = 1.0f / denom;
  if (tid < TT) attn_out[(size_t)b * TT + tid] = e * inv;
}

// ---------------------------------------------------------------------------
// Kernel B: PV. out[b][d] = sum_t attn[b][t] * val[b][t][d].
// ---------------------------------------------------------------------------
__global__ __launch_bounds__(256) void din_pv(
    const float* __restrict__ val, const float* __restrict__ attn,
    float* __restrict__ out) {
  const int b = blockIdx.x;
  const int tid = threadIdx.x;
  __shared__ float eL[TT];
  __shared__ float red[8 * DD];

  if (tid < TT) eL[tid] = attn[(size_t)b * TT + tid];
  __syncthreads();

  const int group = tid >> 5;
  const int d4 = (tid & 31) * 4;
  const float* vb = val + (size_t)b * TT * DD;
  float4 acc4 = make_float4(0.f, 0.f, 0.f, 0.f);
  #pragma unroll 5
  for (int t = group * 25; t < group * 25 + 25; ++t) {
    float4 v = *(const float4*)(vb + (size_t)t * DD + d4);
    float wt = eL[t];
    acc4.x += wt * v.x; acc4.y += wt * v.y;
    acc4.z += wt * v.z; acc4.w += wt * v.w;
  }
  *(float4*)&red[group * DD + d4] = acc4;
  __syncthreads();
  if (tid < DD) {
    float s = 0.0f;
    #pragma unroll
    for (int g = 0; g < 8; ++g) s += red[g * DD + tid];
    out[(size_t)b * DD + tid] = s;
  }
}

extern "C" void kernel_launch(void* const* d_in, const int* in_sizes, int n_in,
                              void* d_out, int out_size, void* d_ws, size_t ws_size,
                              hipStream_t stream) {
  const float* query = (const float*)d_in[0];
  const float* key   = (const float*)d_in[1];
  const float* val   = (const float*)d_in[2];
  const int*   mask  = (const int*)d_in[3];
  const float* W0    = (const float*)d_in[4];
  const float* b0    = (const float*)d_in[5];
  const float* a0    = (const float*)d_in[6];
  const float* W1    = (const float*)d_in[7];
  const float* b1    = (const float*)d_in[8];
  const float* a1    = (const float*)d_in[9];
  const float* Wout  = (const float*)d_in[10];
  const float* bout  = (const float*)d_in[11];
  float* out = (float*)d_out;
  float* ws  = (float*)d_ws;
  float* attn = ws + ATTN_OFF;

  hipLaunchKernelGGL(din_fold, dim3(224), dim3(256), 0, stream, W0, W1, ws);
  hipLaunchKernelGGL(din_logits, dim3(BB), dim3(256), 0, stream,
                     query, key, mask, b0, a0, b1, a1, Wout, bout, ws, attn);
  hipLaunchKernelGGL(din_pv, dim3(BB), dim3(256), 0, stream, val, attn, out);
}

// Round 7
// 197.987 us; speedup vs baseline: 1.8153x; 1.8153x over previous
//
#include <hip/hip_runtime.h>
#include <cstdint>

#define BB 2048
#define TT 200
#define DD 128
#define H1 128
#define H2 64
#define MASK_PAD -4294967295.0f

typedef __attribute__((ext_vector_type(8))) short short8;
typedef __attribute__((ext_vector_type(4))) float floatx4;

#define ATTN_OFF 57344  // float offset of attn[2048][200] in ws

static __device__ __forceinline__ unsigned short f2bf(float x) {
  union { float f; unsigned int u; } v; v.f = x;
  unsigned int r = v.u + 0x7FFF + ((v.u >> 16) & 1);  // RNE
  return (unsigned short)(r >> 16);
}

// ---------------------------------------------------------------------------
// Fold kernel -> ws:
//   Wqac[d][h] = W0a[d][h] + W0c[d][h]          fp32 [128][128] @ float 0
//   WkT [h][d] = (W0b - W0c)[d][h]              fp32 [128][128] @ float 16384
//   WdT [h][d] = W0d[d][h]                      fp32 [128][128] @ float 32768
//   W1tb[g][h] = bf16(W1[h][g])                 bf16 [64][128]  @ float 49152
// ---------------------------------------------------------------------------
__global__ void din_fold(const float* __restrict__ W0,
                         const float* __restrict__ W1,
                         float* __restrict__ ws) {
  int i = blockIdx.x * blockDim.x + threadIdx.x;
  if (i < 16384) {
    int d = i >> 7, h = i & 127;
    ws[i] = W0[d * 128 + h] + W0[(256 + d) * 128 + h];
  } else if (i < 32768) {
    int j = i - 16384; int h = j >> 7, d = j & 127;
    ws[16384 + j] = W0[(128 + d) * 128 + h] - W0[(256 + d) * 128 + h];
  } else if (i < 49152) {
    int j = i - 32768; int h = j >> 7, d = j & 127;
    ws[32768 + j] = W0[(384 + d) * 128 + h];
  } else if (i < 57344) {
    int j = i - 49152; int g = j >> 7, h = j & 127;
    ((unsigned short*)(ws + 49152))[j] = f2bf(W1[h * 64 + g]);
  }
}

// ---------------------------------------------------------------------------
// Kernel A: logits + softmax -> attn. One block per b, 4 independent waves.
// LDS: Wb = bf16(WkT + q_d*WdT) [128x128 swz], W1s [64x128 swz],
//      A2 private transpose buf per wave. Barrier-free main loop; per-tile:
//   prefetch next key tile + this tile's a0/a1 -> GEMM1(fullwidth, B=LDS)
//   -> PReLU -> LDS transpose -> GEMM2(B=LDS) -> PReLU -> reduce -> logit.
// ---------------------------------------------------------------------------
__global__ __launch_bounds__(256, 2) void din_logits(
    const float* __restrict__ query, const float* __restrict__ key,
    const int* __restrict__ mask,
    const float* __restrict__ b0, const float* __restrict__ a0,
    const float* __restrict__ b1, const float* __restrict__ a1,
    const float* __restrict__ Wout, const float* __restrict__ bout,
    const float* __restrict__ ws, float* __restrict__ attn_out) {
  const int b = blockIdx.x;
  const int tid = threadIdx.x;
  const int w = tid >> 6;
  const int l = tid & 63;

  __shared__ unsigned short Wb[128 * 128];    // 32 KB folded W_b bf16 (swz)
  __shared__ unsigned short W1s[64 * 128];    // 16 KB W1^T bf16 (swz)
  __shared__ unsigned short A2[4][16 * 128];  // 16 KB per-wave H0 (swz)
  __shared__ float qs[DD];
  __shared__ float qas[H1];
  __shared__ float logitsAll[208];
  __shared__ float red4[8];

  const float* Wqac = ws;
  const float* WkT  = ws + 16384;
  const float* WdT  = ws + 32768;
  const unsigned short* W1tb = (const unsigned short*)(ws + 49152);

  // ---- stage q ----
  if (tid < DD) qs[tid] = query[(size_t)b * DD + tid];
  __syncthreads();

  // ---- build Wb = bf16(WkT[h][d] + q[d]*WdT[h][d]), swizzled ----
  #pragma unroll
  for (int j = 0; j < 16; ++j) {
    int flat = j * 1024 + tid * 4;
    int h = flat >> 7, d = flat & 127;
    float4 kv = *(const float4*)(WkT + flat);
    float4 dv = *(const float4*)(WdT + flat);
    ushort4 u;
    u.x = f2bf(kv.x + qs[d] * dv.x);
    u.y = f2bf(kv.y + qs[d + 1] * dv.y);
    u.z = f2bf(kv.z + qs[d + 2] * dv.z);
    u.w = f2bf(kv.w + qs[d + 3] * dv.w);
    *(ushort4*)((char*)Wb + h * 256 + ((d * 2) ^ ((h & 7) << 4))) = u;
  }
  // ---- copy W1s (swizzled) ----
  #pragma unroll
  for (int j = 0; j < 8; ++j) {
    int flat = j * 1024 + tid * 4;
    int g = flat >> 7, h = flat & 127;
    ushort4 u = *(const ushort4*)(W1tb + flat);
    *(ushort4*)((char*)W1s + g * 256 + ((h * 2) ^ ((g & 7) << 4))) = u;
  }
  // ---- qA ----
  if (tid < H1) {
    float acc = b0[tid];
    const float* wq = Wqac + tid;
    #pragma unroll 8
    for (int d = 0; d < DD; ++d) acc += qs[d] * wq[d * 128];
    qas[tid] = acc;
  }
  __syncthreads();  // Wb, W1s, qas ready — last barrier before softmax

  const int kgrp = l >> 4;            // 0..3
  const int lr = l & 15;
  char* a2b = (char*)A2[w];

  // per-lane epilogue-2 constants (g-cols this lane owns)
  float b1v[4], wov[4];
  #pragma unroll
  for (int nt = 0; nt < 4; ++nt) {
    int g = nt * 16 + lr;
    b1v[nt] = b1[g]; wov[nt] = Wout[g];
  }
  const float bout0 = bout[0];

  // ---- prologue: prefetch first tile's key chunk ----
  float4 fa[8];
  int mt = w;
  {
    int trow = mt * 16 + lr; if (trow > 199) trow = 199;
    const float* ar = key + ((size_t)b * TT + trow) * DD + kgrp * 8;
    #pragma unroll
    for (int ks = 0; ks < 4; ++ks) {
      fa[2 * ks]     = *(const float4*)(ar + ks * 32);
      fa[2 * ks + 1] = *(const float4*)(ar + ks * 32 + 4);
    }
  }

  // =============== barrier-free per-wave M-tile loop ===============
  #pragma unroll 1
  while (mt < 13) {
    // ---- convert prefetched key to bf16 A-frags ----
    short8 af[4];
    #pragma unroll
    for (int ks = 0; ks < 4; ++ks) {
      float4 f0 = fa[2 * ks], f1 = fa[2 * ks + 1];
      short8 t;
      t[0] = (short)f2bf(f0.x); t[1] = (short)f2bf(f0.y);
      t[2] = (short)f2bf(f0.z); t[3] = (short)f2bf(f0.w);
      t[4] = (short)f2bf(f1.x); t[5] = (short)f2bf(f1.y);
      t[6] = (short)f2bf(f1.z); t[7] = (short)f2bf(f1.w);
      af[ks] = t;
    }
    // ---- prefetch NEXT tile's key (hidden under this tile's compute) ----
    int mtn = mt + 4;
    if (mtn < 13) {
      int trow = mtn * 16 + lr; if (trow > 199) trow = 199;
      const float* ar = key + ((size_t)b * TT + trow) * DD + kgrp * 8;
      #pragma unroll
      for (int ks = 0; ks < 4; ++ks) {
        fa[2 * ks]     = *(const float4*)(ar + ks * 32);
        fa[2 * ks + 1] = *(const float4*)(ar + ks * 32 + 4);
      }
    }
    // ---- issue a0/a1 loads for THIS tile (hide under GEMM1) ----
    float a0v[8][4], a1v[4][4];
    #pragma unroll
    for (int r = 0; r < 4; ++r) {
      int tg = mt * 16 + kgrp * 4 + r; if (tg > 199) tg = 199;
      #pragma unroll
      for (int nt = 0; nt < 8; ++nt)
        a0v[nt][r] = a0[tg * H1 + nt * 16 + lr];
      #pragma unroll
      for (int nt = 0; nt < 4; ++nt)
        a1v[nt][r] = a1[tg * H2 + nt * 16 + lr];
    }

    // ---- GEMM1: full width (8 n-tiles), B from LDS ----
    floatx4 acc1[8];
    #pragma unroll
    for (int nt = 0; nt < 8; ++nt) acc1[nt] = (floatx4)(0.0f);
    #pragma unroll
    for (int ks = 0; ks < 4; ++ks) {
      #pragma unroll
      for (int nt = 0; nt < 8; ++nt) {
        int h = nt * 16 + lr;
        short8 bf = *(const short8*)((const char*)Wb + h * 256 +
                                     ((ks * 64 + kgrp * 16) ^ ((h & 7) << 4)));
        acc1[nt] = __builtin_amdgcn_mfma_f32_16x16x32_bf16(af[ks], bf, acc1[nt], 0, 0, 0);
      }
    }
    // ---- epilogue 1: +qA, PReLU(a0), write H0 to private LDS (swz) ----
    #pragma unroll
    for (int nt = 0; nt < 8; ++nt) {
      int h = nt * 16 + lr;
      float qa = qas[h];
      #pragma unroll
      for (int r = 0; r < 4; ++r) {
        int t_loc = kgrp * 4 + r;
        float v = acc1[nt][r] + qa;
        float a = a0v[nt][r];
        v = v > 0.0f ? v : a * v;
        *(unsigned short*)(a2b + t_loc * 256 + ((h * 2) ^ ((t_loc & 7) << 4))) = f2bf(v);
      }
    }
    // ---- GEMM2: A from private LDS, B from LDS W1s ----
    short8 a2f[4];
    #pragma unroll
    for (int ks = 0; ks < 4; ++ks) {
      a2f[ks] = *(const short8*)(a2b + lr * 256 +
                                 ((ks * 64 + kgrp * 16) ^ ((lr & 7) << 4)));
    }
    floatx4 acc2[4];
    #pragma unroll
    for (int nt = 0; nt < 4; ++nt) acc2[nt] = (floatx4)(0.0f);
    #pragma unroll
    for (int ks = 0; ks < 4; ++ks) {
      #pragma unroll
      for (int nt = 0; nt < 4; ++nt) {
        int g = nt * 16 + lr;
        short8 bf = *(const short8*)((const char*)W1s + g * 256 +
                                     ((ks * 64 + kgrp * 16) ^ ((g & 7) << 4)));
        acc2[nt] = __builtin_amdgcn_mfma_f32_16x16x32_bf16(a2f[ks], bf, acc2[nt], 0, 0, 0);
      }
    }
    // ---- epilogue 2: +b1, PReLU(a1), *Wout, 16-lane reduce -> logits ----
    float p[4] = {0.f, 0.f, 0.f, 0.f};
    #pragma unroll
    for (int nt = 0; nt < 4; ++nt) {
      #pragma unroll
      for (int r = 0; r < 4; ++r) {
        float x = acc2[nt][r] + b1v[nt];
        float a = a1v[nt][r];
        x = x > 0.0f ? x : a * x;
        p[r] += x * wov[nt];
      }
    }
    #pragma unroll
    for (int m = 1; m < 16; m <<= 1) {
      #pragma unroll
      for (int r = 0; r < 4; ++r) p[r] += __shfl_xor(p[r], m);
    }
    if (lr == 0) {
      #pragma unroll
      for (int r = 0; r < 4; ++r) {
        int tg = mt * 16 + kgrp * 4 + r;
        if (tg < TT) {
          int mk = mask[(size_t)b * TT + tg];
          logitsAll[tg] = (mk == 0) ? MASK_PAD : (bout0 + p[r]);
        }
      }
    }
    mt = mtn;
  }
  __syncthreads();

  // =================== softmax -> normalized attn ===================
  float lv = (tid < TT) ? logitsAll[tid] : -INFINITY;
  {
    float m = lv;
    #pragma unroll
    for (int off = 32; off >= 1; off >>= 1) m = fmaxf(m, __shfl_xor(m, off));
    if (l == 0) red4[w] = m;
  }
  __syncthreads();
  float mx = fmaxf(fmaxf(red4[0], red4[1]), fmaxf(red4[2], red4[3]));
  float e = (tid < TT) ? __expf(lv - mx) : 0.0f;
  {
    float s = e;
    #pragma unroll
    for (int off = 32; off >= 1; off >>= 1) s += __shfl_xor(s, off);
    if (l == 0) red4[4 + w] = s;
  }
  __syncthreads();
  float denom = red4[4] + red4[5] + red4[6] + red4[7];
  float inv = 1.0f / denom;
  if (tid < TT) attn_out[(size_t)b * TT + tid] = e * inv;
}

// ---------------------------------------------------------------------------
// Kernel B: PV. out[b][d] = sum_t attn[b][t] * val[b][t][d].
// ---------------------------------------------------------------------------
__global__ __launch_bounds__(256) void din_pv(
    const float* __restrict__ val, const float* __restrict__ attn,
    float* __restrict__ out) {
  const int b = blockIdx.x;
  const int tid = threadIdx.x;
  __shared__ float eL[TT];
  __shared__ float red[8 * DD];

  if (tid < TT) eL[tid] = attn[(size_t)b * TT + tid];
  __syncthreads();

  const int group = tid >> 5;
  const int d4 = (tid & 31) * 4;
  const float* vb = val + (size_t)b * TT * DD;
  float4 acc4 = make_float4(0.f, 0.f, 0.f, 0.f);
  #pragma unroll 5
  for (int t = group * 25; t < group * 25 + 25; ++t) {
    float4 v = *(const float4*)(vb + (size_t)t * DD + d4);
    float wt = eL[t];
    acc4.x += wt * v.x; acc4.y += wt * v.y;
    acc4.z += wt * v.z; acc4.w += wt * v.w;
  }
  *(float4*)&red[group * DD + d4] = acc4;
  __syncthreads();
  if (tid < DD) {
    float s = 0.0f;
    #pragma unroll
    for (int g = 0; g < 8; ++g) s += red[g * DD + tid];
    out[(size_t)b * DD + tid] = s;
  }
}

extern "C" void kernel_launch(void* const* d_in, const int* in_sizes, int n_in,
                              void* d_out, int out_size, void* d_ws, size_t ws_size,
                              hipStream_t stream) {
  const float* query = (const float*)d_in[0];
  const float* key   = (const float*)d_in[1];
  const float* val   = (const float*)d_in[2];
  const int*   mask  = (const int*)d_in[3];
  const float* W0    = (const float*)d_in[4];
  const float* b0    = (const float*)d_in[5];
  const float* a0    = (const float*)d_in[6];
  const float* W1    = (const float*)d_in[7];
  const float* b1    = (const float*)d_in[8];
  const float* a1    = (const float*)d_in[9];
  const float* Wout  = (const float*)d_in[10];
  const float* bout  = (const float*)d_in[11];
  float* out = (float*)d_out;
  float* ws  = (float*)d_ws;
  float* attn = ws + ATTN_OFF;

  hipLaunchKernelGGL(din_fold, dim3(224), dim3(256), 0, stream, W0, W1, ws);
  hipLaunchKernelGGL(din_logits, dim3(BB), dim3(256), 0, stream,
                     query, key, mask, b0, a0, b1, a1, Wout, bout, ws, attn);
  hipLaunchKernelGGL(din_pv, dim3(BB), dim3(256), 0, stream, val, attn, out);
}